// Round 4
// baseline (61.412 us; speedup 1.0000x reference)
//
#include <hip/hip_runtime.h>

#define WW 512
#define HWSZ (512 * 512)
#define LTOT 65536
#define EPSV 1e-6f
#define TP 64            // patches per block (one row, 64 consecutive patch columns = 512B/row)
#define NTHREADS 1024

typedef float v2f __attribute__((ext_vector_type(2)));
typedef float v4f __attribute__((ext_vector_type(4)));

// One block owns 64 patches (128 input columns) across ALL 256 channels.
// Thread t: k = t&31 (float4 quad -> patches 2k,2k+1), cb = t>>5 (channel base 0..31),
// channels c = cb + 32*it for it=0..7; float4 row pairs KEPT in registers (64 floats).
// Wave-load = 2 contiguous 512B segments. Input is read exactly once -> nontemporal.
__global__ __launch_bounds__(NTHREADS) void fused_kernel(const float* __restrict__ x,
                                                         float* __restrict__ out) {
    const int t = threadIdx.x;
    const int k = t & 31;          // quad index: columns 4k..4k+3 -> patches 2k, 2k+1
    const int cb = t >> 5;         // 0..31
    const int l0 = blockIdx.x * TP;
    const int i = l0 >> 8;         // patch row
    const int j0 = l0 & 255;       // patch col base (multiple of 64)

    const float* base = x + (size_t)(2 * i) * WW + 2 * j0 + 4 * k;

    v4f A[8], B[8];
    float s0 = 0.f, s1 = 0.f, s2 = 0.f, s3 = 0.f;
    float s4 = 0.f, s5 = 0.f, s6 = 0.f, s7 = 0.f;

#pragma unroll
    for (int it = 0; it < 8; ++it) {
        const int c = cb + 32 * it;
        const float* pc = base + (size_t)c * HWSZ;
        const v4f a = __builtin_nontemporal_load((const v4f*)(pc));       // row 2i
        const v4f b = __builtin_nontemporal_load((const v4f*)(pc + WW));  // row 2i+1
        A[it] = a;
        B[it] = b;
        const float m0 = (a.x + a.y + b.x + b.y) * 0.25f;
        const float m1 = (a.z + a.w + b.z + b.w) * 0.25f;
        float e;
        e = a.x - m0 + EPSV; s0 += e * e;
        e = a.y - m0 + EPSV; s1 += e * e;
        e = b.x - m0 + EPSV; s2 += e * e;
        e = b.y - m0 + EPSV; s3 += e * e;
        e = a.z - m1 + EPSV; s4 += e * e;
        e = a.w - m1 + EPSV; s5 += e * e;
        e = b.z - m1 + EPSV; s6 += e * e;
        e = b.w - m1 + EPSV; s7 += e * e;
    }

    // Lane l and l^32 share k, differ in cb -> one shfl folds them.
    s0 += __shfl_xor(s0, 32);
    s1 += __shfl_xor(s1, 32);
    s2 += __shfl_xor(s2, 32);
    s3 += __shfl_xor(s3, 32);
    s4 += __shfl_xor(s4, 32);
    s5 += __shfl_xor(s5, 32);
    s6 += __shfl_xor(s6, 32);
    s7 += __shfl_xor(s7, 32);

    __shared__ float part[16][32][8];   // [wave][k][patchhalf*4 + e]  (16 KiB)
    __shared__ int sidx[TP];

    const int wave = t >> 6;
    if ((t & 63) < 32) {                // lanes 0..31 carry k = lane
        float* p = part[wave][k];
        p[0] = s0; p[1] = s1; p[2] = s2; p[3] = s3;
        p[4] = s4; p[5] = s5; p[6] = s6; p[7] = s7;
    }
    __syncthreads();

    if (t < TP) {                       // one thread per patch: sum 16 waves (b128 reads), argmax of 4
        const int kk = t >> 1;
        const int hf = (t & 1) * 4;
        v4f D = {0.f, 0.f, 0.f, 0.f};
#pragma unroll
        for (int w = 0; w < 16; ++w) {
            D += *(const v4f*)(part[w][kk] + hf);
        }
        int best = 0;
        float bv = D.x;
        if (D.y > bv) { bv = D.y; best = 1; }
        if (D.z > bv) { bv = D.z; best = 2; }
        if (D.w > bv) { bv = D.w; best = 3; }
        sidx[t] = best;
    }
    __syncthreads();

    const int e0 = sidx[2 * k];
    const int e1 = sidx[2 * k + 1];

#pragma unroll
    for (int it = 0; it < 8; ++it) {
        const int c = cb + 32 * it;
        const v4f a = A[it];
        const v4f b = B[it];
        const float v0 = (e0 == 0) ? a.x : (e0 == 1) ? a.y : (e0 == 2) ? b.x : b.y;
        const float v1 = (e1 == 0) ? a.z : (e1 == 1) ? a.w : (e1 == 2) ? b.z : b.w;
        v2f v;
        v.x = v0;
        v.y = v1;
        __builtin_nontemporal_store(v, (v2f*)(out + (size_t)c * LTOT + l0 + 2 * k));
    }
}

extern "C" void kernel_launch(void* const* d_in, const int* in_sizes, int n_in,
                              void* d_out, int out_size, void* d_ws, size_t ws_size,
                              hipStream_t stream) {
    const float* x = (const float*)d_in[0];
    float* out = (float*)d_out;
    fused_kernel<<<LTOT / TP, NTHREADS, 0, stream>>>(x, out);
}

// Round 5
// 57.996 us; speedup vs baseline: 1.0589x; 1.0589x over previous
//
#include <hip/hip_runtime.h>

#define WW 512
#define HWSZ (512 * 512)
#define LTOT 65536
#define EPSV 1e-6f
#define TP 64            // patches per block (one row, 64 consecutive patch columns = 512B/row)
#define NTHREADS 1024

typedef float v2f __attribute__((ext_vector_type(2)));

// One block owns 64 patches (128 input columns) across ALL 256 channels.
// Thread t: k = t&31 (float4 quad -> patches 2k,2k+1), cb = t>>5 (channel base 0..31),
// channels c = cb + 32*it for it=0..7; float4 row pairs KEPT in registers (64 floats).
// Wave-load = 2 contiguous 512B segments (lanes 0-31 one channel-row, 32-63 the next).
// NOTE R4: nontemporal LOADS regressed 57.8->61.4us (evict-first defeats short-range
// L2 sector reuse); plain loads + nontemporal stores is the fastest measured combo.
__global__ __launch_bounds__(NTHREADS) void fused_kernel(const float* __restrict__ x,
                                                         float* __restrict__ out) {
    const int t = threadIdx.x;
    const int k = t & 31;          // quad index: columns 4k..4k+3 -> patches 2k, 2k+1
    const int cb = t >> 5;         // 0..31
    const int l0 = blockIdx.x * TP;
    const int i = l0 >> 8;         // patch row
    const int j0 = l0 & 255;       // patch col base (multiple of 64)

    const float* base = x + (size_t)(2 * i) * WW + 2 * j0 + 4 * k;

    float4 A[8], B[8];
    float s0 = 0.f, s1 = 0.f, s2 = 0.f, s3 = 0.f;
    float s4 = 0.f, s5 = 0.f, s6 = 0.f, s7 = 0.f;

#pragma unroll
    for (int it = 0; it < 8; ++it) {
        const int c = cb + 32 * it;
        const float* pc = base + (size_t)c * HWSZ;
        const float4 a = *(const float4*)(pc);        // row 2i:   patch 2k (.x,.y), 2k+1 (.z,.w)
        const float4 b = *(const float4*)(pc + WW);   // row 2i+1
        A[it] = a;
        B[it] = b;
        const float m0 = (a.x + a.y + b.x + b.y) * 0.25f;
        const float m1 = (a.z + a.w + b.z + b.w) * 0.25f;
        float e;
        e = a.x - m0 + EPSV; s0 += e * e;
        e = a.y - m0 + EPSV; s1 += e * e;
        e = b.x - m0 + EPSV; s2 += e * e;
        e = b.y - m0 + EPSV; s3 += e * e;
        e = a.z - m1 + EPSV; s4 += e * e;
        e = a.w - m1 + EPSV; s5 += e * e;
        e = b.z - m1 + EPSV; s6 += e * e;
        e = b.w - m1 + EPSV; s7 += e * e;
    }

    // Lane l and l^32 share k, differ in cb -> one shfl folds them.
    s0 += __shfl_xor(s0, 32);
    s1 += __shfl_xor(s1, 32);
    s2 += __shfl_xor(s2, 32);
    s3 += __shfl_xor(s3, 32);
    s4 += __shfl_xor(s4, 32);
    s5 += __shfl_xor(s5, 32);
    s6 += __shfl_xor(s6, 32);
    s7 += __shfl_xor(s7, 32);

    __shared__ float part[16][32][8];   // [wave][k][patchhalf*4 + e]  (16 KiB)
    __shared__ int sidx[TP];

    const int wave = t >> 6;
    if ((t & 63) < 32) {                // lanes 0..31 carry k = lane
        float* p = part[wave][k];
        p[0] = s0; p[1] = s1; p[2] = s2; p[3] = s3;
        p[4] = s4; p[5] = s5; p[6] = s6; p[7] = s7;
    }
    __syncthreads();

    if (t < TP) {                       // one thread per patch: sum 16 waves, argmax of 4
        const int kk = t >> 1;
        const int hf = (t & 1) * 4;
        float D0 = 0.f, D1 = 0.f, D2 = 0.f, D3 = 0.f;
#pragma unroll
        for (int w = 0; w < 16; ++w) {
            const float* p = part[w][kk] + hf;
            D0 += p[0];
            D1 += p[1];
            D2 += p[2];
            D3 += p[3];
        }
        int best = 0;
        float bv = D0;
        if (D1 > bv) { bv = D1; best = 1; }
        if (D2 > bv) { bv = D2; best = 2; }
        if (D3 > bv) { bv = D3; best = 3; }
        sidx[t] = best;
    }
    __syncthreads();

    const int e0 = sidx[2 * k];
    const int e1 = sidx[2 * k + 1];

#pragma unroll
    for (int it = 0; it < 8; ++it) {
        const int c = cb + 32 * it;
        const float4 a = A[it];
        const float4 b = B[it];
        const float v0 = (e0 == 0) ? a.x : (e0 == 1) ? a.y : (e0 == 2) ? b.x : b.y;
        const float v1 = (e1 == 0) ? a.z : (e1 == 1) ? a.w : (e1 == 2) ? b.z : b.w;
        v2f v;
        v.x = v0;
        v.y = v1;
        __builtin_nontemporal_store(v, (v2f*)(out + (size_t)c * LTOT + l0 + 2 * k));
    }
}

extern "C" void kernel_launch(void* const* d_in, const int* in_sizes, int n_in,
                              void* d_out, int out_size, void* d_ws, size_t ws_size,
                              hipStream_t stream) {
    const float* x = (const float*)d_in[0];
    float* out = (float*)d_out;
    fused_kernel<<<LTOT / TP, NTHREADS, 0, stream>>>(x, out);
}